// Round 7
// baseline (916.363 us; speedup 1.0000x reference)
//
#include <hip/hip_runtime.h>
#include <cstdint>
#include <cstddef>

#define N_NODES 100000
#define N_EDGES 1600000

// ---------------- workspace layout (byte offsets) ----------------
#define WS_ROWPTR   0            // (N+1) int
#define WS_DEG      400384       // N int
#define WS_FILL     800768       // N int
#define WS_INVDEG   1201152      // N float
#define WS_BSUM     1601536      // 98 int
#define WS_FLAG     1602560      // 1 int (1 = edge_index is int64)
#define WS_WLT0     1602816      // 128x128 f (transposed [k][o])
#define WS_WRT0     1668352
#define WS_WLT1     1733888
#define WS_WRT1     1799424
#define WS_WCT2     1864960      // 128x80 f ([k][o], o<40 -> Wl2, o>=40 -> Wr2)
#define WS_COL      1906176      // E int
#define WS_AGG      8306432      // N*128 f
#define WS_H1       59506432     // N*128 f
#define WS_H2       110706432    // N*128 f
#define WS_P        WS_AGG              // overlay (agg dead after layer-1 GEMM)
#define WS_R        (WS_AGG + 16000000) // N*40 f

__device__ __forceinline__ int edge_val(const void* ei, long long idx, int m64) {
    return m64 ? (int)((const long long*)ei)[idx] : ((const int*)ei)[idx];
}

// detect int32 vs int64 edge_index: int64 -> all odd 32-bit words are zero
__global__ void k_detect(const void* __restrict__ ei, int* __restrict__ flag) {
    __shared__ int s_any;
    if (threadIdx.x == 0) s_any = 0;
    __syncthreads();
    const int* p = (const int*)ei;
    int any = 0;
    for (int j = 0; j < 8; ++j) any |= p[2 * (threadIdx.x * 8 + j) + 1];
    if (any) s_any = 1;   // benign race: all writers write 1
    __syncthreads();
    if (threadIdx.x == 0) *flag = (s_any == 0) ? 1 : 0;
}

__global__ void k_transpose(const float* __restrict__ Wl0, const float* __restrict__ Wr0,
                            const float* __restrict__ Wl1, const float* __restrict__ Wr1,
                            const float* __restrict__ Wl2, const float* __restrict__ Wr2,
                            float* __restrict__ T0, float* __restrict__ T1,
                            float* __restrict__ T2, float* __restrict__ T3,
                            float* __restrict__ Tc) {
    int i = blockIdx.x * 256 + threadIdx.x;
    if (i < 16384) {
        int o = i >> 7, k = i & 127;
        int d = k * 128 + o;
        T0[d] = Wl0[i]; T1[d] = Wr0[i]; T2[d] = Wl1[i]; T3[d] = Wr1[i];
    }
    if (i < 10240) {
        int k = i / 80, o = i % 80;
        Tc[i] = (o < 40) ? Wl2[o * 128 + k] : Wr2[(o - 40) * 128 + k];
    }
}

__global__ void k_hist(const void* __restrict__ ei, const int* __restrict__ flag,
                       int* __restrict__ deg) {
    int m = *flag;
    int e = blockIdx.x * blockDim.x + threadIdx.x;
    if (e < N_EDGES) {
        int d = edge_val(ei, (long long)N_EDGES + e, m);
        atomicAdd(&deg[d], 1);
    }
}

__global__ void k_scan1(const int* __restrict__ deg, int* __restrict__ bsum) {
    __shared__ int sd[256];
    int t = threadIdx.x;
    int i0 = blockIdx.x * 1024 + t * 4;
    int s = 0;
    #pragma unroll
    for (int j = 0; j < 4; ++j) if (i0 + j < N_NODES) s += deg[i0 + j];
    sd[t] = s; __syncthreads();
    for (int off = 128; off; off >>= 1) {
        if (t < off) sd[t] += sd[t + off];
        __syncthreads();
    }
    if (t == 0) bsum[blockIdx.x] = sd[0];
}

__global__ void k_scan2(int* __restrict__ bsum, int* __restrict__ row_ptr, int nb) {
    if (threadIdx.x == 0 && blockIdx.x == 0) {
        int run = 0;
        for (int i = 0; i < nb; ++i) { int v = bsum[i]; bsum[i] = run; run += v; }
        row_ptr[N_NODES] = run;
    }
}

__global__ void k_scan3(const int* __restrict__ deg, const int* __restrict__ bsum,
                        int* __restrict__ row_ptr) {
    __shared__ int sd[256];
    int t = threadIdx.x;
    int i0 = blockIdx.x * 1024 + t * 4;
    int v[4]; int s = 0;
    #pragma unroll
    for (int j = 0; j < 4; ++j) { v[j] = (i0 + j < N_NODES) ? deg[i0 + j] : 0; s += v[j]; }
    sd[t] = s; __syncthreads();
    for (int off = 1; off < 256; off <<= 1) {
        int x = 0;
        if (t >= off) x = sd[t - off];
        __syncthreads();
        sd[t] += x;
        __syncthreads();
    }
    int run = bsum[blockIdx.x] + sd[t] - s;   // exclusive prefix for this thread
    #pragma unroll
    for (int j = 0; j < 4; ++j) {
        if (i0 + j < N_NODES) row_ptr[i0 + j] = run;
        run += v[j];
    }
}

__global__ void k_invdeg(const int* __restrict__ row_ptr, float* __restrict__ invd) {
    int i = blockIdx.x * 256 + threadIdx.x;
    if (i < N_NODES) {
        int d = row_ptr[i + 1] - row_ptr[i];
        invd[i] = 1.0f / (float)(d > 1 ? d : 1);
    }
}

__global__ void k_scatter(const void* __restrict__ ei, const int* __restrict__ flag,
                          const int* __restrict__ row_ptr, int* __restrict__ fill,
                          int* __restrict__ col) {
    int m = *flag;
    int e = blockIdx.x * blockDim.x + threadIdx.x;
    if (e < N_EDGES) {
        int s = edge_val(ei, e, m);
        int d = edge_val(ei, (long long)N_EDGES + e, m);
        int pos = row_ptr[d] + atomicAdd(&fill[d], 1);
        col[pos] = s;
    }
}

// mean-aggregate 128-dim rows: one wave per node, float2 per lane, 8 edges in flight
__global__ __launch_bounds__(256) void k_aggregate(
    const float* __restrict__ h, const int* __restrict__ rowp,
    const int* __restrict__ col, const float* __restrict__ invd,
    float* __restrict__ agg) {
    int w = blockIdx.x * 4 + (threadIdx.x >> 6);
    if (w >= N_NODES) return;
    int lane = threadIdx.x & 63;
    const float2* hp = (const float2*)h;
    int beg = rowp[w], end = rowp[w + 1];
    float x = 0.f, y = 0.f;
    int e = beg;
    for (; e + 8 <= end; e += 8) {
        int s0 = col[e], s1 = col[e + 1], s2 = col[e + 2], s3 = col[e + 3];
        int s4 = col[e + 4], s5 = col[e + 5], s6 = col[e + 6], s7 = col[e + 7];
        float2 a = hp[(size_t)s0 * 64 + lane];
        float2 b = hp[(size_t)s1 * 64 + lane];
        float2 c = hp[(size_t)s2 * 64 + lane];
        float2 d = hp[(size_t)s3 * 64 + lane];
        float2 a2 = hp[(size_t)s4 * 64 + lane];
        float2 b2 = hp[(size_t)s5 * 64 + lane];
        float2 c2 = hp[(size_t)s6 * 64 + lane];
        float2 d2 = hp[(size_t)s7 * 64 + lane];
        x += (a.x + b.x) + (c.x + d.x) + (a2.x + b2.x) + (c2.x + d2.x);
        y += (a.y + b.y) + (c.y + d.y) + (a2.y + b2.y) + (c2.y + d2.y);
    }
    for (; e + 4 <= end; e += 4) {
        int s0 = col[e], s1 = col[e + 1], s2 = col[e + 2], s3 = col[e + 3];
        float2 a = hp[(size_t)s0 * 64 + lane];
        float2 b = hp[(size_t)s1 * 64 + lane];
        float2 c = hp[(size_t)s2 * 64 + lane];
        float2 d = hp[(size_t)s3 * 64 + lane];
        x += (a.x + b.x) + (c.x + d.x);
        y += (a.y + b.y) + (c.y + d.y);
    }
    for (; e < end; ++e) {
        float2 a = hp[(size_t)col[e] * 64 + lane];
        x += a.x; y += a.y;
    }
    float id = invd[w];
    ((float2*)agg)[(size_t)w * 64 + lane] = make_float2(x * id, y * id);
}

// fused: out = relu(l2norm(agg@WlT + h@WrT + b)); 64 nodes/block, 256 thr.
// Wave owns 16 nodes; lane owns 2 outs (o2=lane*2). V (the broadcast operand)
// is staged by EACH WAVE into its private 8KB LDS region with coalesced vector
// loads, then read back as same-address b128 broadcasts (free, in-order DS
// pipe -> fine-grained lgkmcnt). W is read straight from global (coalesced
// 512B/instr, 64KB stream, L1/L2-resident, vmcnt-pipelined). ZERO barriers.
// (R6's s_load-V was capped by out-of-order scalar returns forcing
// lgkmcnt(0) drains shared with the W ds_reads.)
__global__ __launch_bounds__(256, 4) void k_gemm_fused(
    const float* __restrict__ agg, const float* __restrict__ hin,
    const float* __restrict__ WlT, const float* __restrict__ WrT,
    const float* __restrict__ bias, float* __restrict__ hout) {
    __shared__ float sV[4 * 16 * 128];   // 32 KB, 8KB per wave
    const int t = threadIdx.x;
    const int lane = t & 63;
    const int o2 = lane * 2;
    const int wv = t >> 6;               // 0..3
    float* myV = sV + wv * 2048;
    int nb = blockIdx.x * 64 + wv * 16;
    if (nb > N_NODES - 16) nb = N_NODES - 16;   // tail waves recompute identical rows — benign

    float acc[16][2];
    const float2 bv = *(const float2*)(bias + o2);
    #pragma unroll
    for (int j = 0; j < 16; ++j) { acc[j][0] = bv.x; acc[j][1] = bv.y; }

    for (int ph = 0; ph < 2; ++ph) {
        // stage this wave's 16 V rows (8KB) into its private LDS region, coalesced
        const float4* Vg = (const float4*)((ph ? hin : agg) + (size_t)nb * 128);
        float4* sV4 = (float4*)myV;
        #pragma unroll
        for (int r = 0; r < 8; ++r)
            sV4[r * 64 + lane] = Vg[r * 64 + lane];
        __builtin_amdgcn_wave_barrier();   // pin stage->read order (wave-synchronous LDS)

        const float* WT = ph ? WrT : WlT;
        #pragma unroll 2
        for (int kq = 0; kq < 32; ++kq) {
            const int k = kq * 4;
            float2 w0 = *(const float2*)(WT + (k + 0) * 128 + o2);
            float2 w1 = *(const float2*)(WT + (k + 1) * 128 + o2);
            float2 w2 = *(const float2*)(WT + (k + 2) * 128 + o2);
            float2 w3 = *(const float2*)(WT + (k + 3) * 128 + o2);
            #pragma unroll
            for (int j = 0; j < 16; ++j) {
                float4 v = *(const float4*)(myV + j * 128 + k);   // uniform -> LDS broadcast
                acc[j][0] = fmaf(v.x, w0.x, fmaf(v.y, w1.x, fmaf(v.z, w2.x, fmaf(v.w, w3.x, acc[j][0]))));
                acc[j][1] = fmaf(v.x, w0.y, fmaf(v.y, w1.y, fmaf(v.z, w2.y, fmaf(v.w, w3.y, acc[j][1]))));
            }
        }
        __builtin_amdgcn_wave_barrier();   // keep next phase's stores after this phase's reads
    }
    // epilogue: L2-normalize each node row (128 outs spread across the 64 lanes), relu, store
    #pragma unroll
    for (int j = 0; j < 16; ++j) {
        float ss = acc[j][0] * acc[j][0] + acc[j][1] * acc[j][1];
        #pragma unroll
        for (int m = 1; m < 64; m <<= 1) ss += __shfl_xor(ss, m, 64);
        float sc = 1.0f / fmaxf(sqrtf(ss), 1e-12f);
        float2 r = make_float2(fmaxf(acc[j][0] * sc, 0.f), fmaxf(acc[j][1] * sc, 0.f));
        *(float2*)(hout + (size_t)(nb + j) * 128 + o2) = r;
    }
}

// layer 2: P = h@Wl2T ; R = h@Wr2T + b2   (80 outs, cat-W in LDS)
__global__ __launch_bounds__(320, 2) void k_gemm2(
    const float* __restrict__ h, const float* __restrict__ WcatT,
    const float* __restrict__ b2, float* __restrict__ P, float* __restrict__ R) {
    __shared__ float sW[128 * 80];
    const int t = threadIdx.x;
    const int o4 = (t % 20) * 4;           // 0..76
    const int ng = t / 20;                 // 0..15
    const int nb = blockIdx.x * 128 + ng * 8;
    #pragma unroll
    for (int j = 0; j < 8; ++j)
        ((float4*)sW)[t + 320 * j] = ((const float4*)WcatT)[t + 320 * j];
    __syncthreads();
    float4 binit = make_float4(0.f, 0.f, 0.f, 0.f);
    if (o4 >= 40) binit = *(const float4*)(b2 + (o4 - 40));
    float acc[8][4];
    #pragma unroll
    for (int j = 0; j < 8; ++j) { acc[j][0] = binit.x; acc[j][1] = binit.y; acc[j][2] = binit.z; acc[j][3] = binit.w; }
    const float4* vrow[8];
    #pragma unroll
    for (int j = 0; j < 8; ++j) {
        int n = nb + j; n = n < N_NODES ? n : N_NODES - 1;
        vrow[j] = (const float4*)(h + (size_t)n * 128);
    }
    #pragma unroll 4
    for (int kq = 0; kq < 32; ++kq) {
        const int k = kq * 4;
        float4 w0 = *(const float4*)(sW + (k + 0) * 80 + o4);
        float4 w1 = *(const float4*)(sW + (k + 1) * 80 + o4);
        float4 w2 = *(const float4*)(sW + (k + 2) * 80 + o4);
        float4 w3 = *(const float4*)(sW + (k + 3) * 80 + o4);
        #pragma unroll
        for (int j = 0; j < 8; ++j) {
            float4 v = vrow[j][kq];
            acc[j][0] = fmaf(v.x, w0.x, fmaf(v.y, w1.x, fmaf(v.z, w2.x, fmaf(v.w, w3.x, acc[j][0]))));
            acc[j][1] = fmaf(v.x, w0.y, fmaf(v.y, w1.y, fmaf(v.z, w2.y, fmaf(v.w, w3.y, acc[j][1]))));
            acc[j][2] = fmaf(v.x, w0.z, fmaf(v.y, w1.z, fmaf(v.z, w2.z, fmaf(v.w, w3.z, acc[j][2]))));
            acc[j][3] = fmaf(v.x, w0.w, fmaf(v.y, w1.w, fmaf(v.z, w2.w, fmaf(v.w, w3.w, acc[j][3]))));
        }
    }
    #pragma unroll
    for (int j = 0; j < 8; ++j) {
        int n = nb + j;
        if (n < N_NODES) {
            float4 r = make_float4(acc[j][0], acc[j][1], acc[j][2], acc[j][3]);
            if (o4 < 40) *(float4*)(P + (size_t)n * 40 + o4) = r;
            else         *(float4*)(R + (size_t)n * 40 + (o4 - 40)) = r;
        }
    }
}

// final: logits = mean_agg(P[src]) + R; softmax over 40; one wave per node
__global__ __launch_bounds__(256) void k_final(
    const float* __restrict__ P, const float* __restrict__ R,
    const int* __restrict__ rowp, const int* __restrict__ col,
    const float* __restrict__ invd, float* __restrict__ out) {
    int w = blockIdx.x * 4 + (threadIdx.x >> 6);
    if (w >= N_NODES) return;
    int lane = threadIdx.x & 63;
    bool act = lane < 40;
    int beg = rowp[w], end = rowp[w + 1];
    float a0 = 0.f, a1 = 0.f, a2 = 0.f, a3 = 0.f;
    int e = beg;
    for (; e + 4 <= end; e += 4) {
        int s0 = col[e], s1 = col[e + 1], s2 = col[e + 2], s3 = col[e + 3];
        if (act) {
            a0 += P[(size_t)s0 * 40 + lane];
            a1 += P[(size_t)s1 * 40 + lane];
            a2 += P[(size_t)s2 * 40 + lane];
            a3 += P[(size_t)s3 * 40 + lane];
        }
    }
    for (; e < end; ++e) if (act) a0 += P[(size_t)col[e] * 40 + lane];
    float acc = (a0 + a1) + (a2 + a3);
    float v = act ? (acc * invd[w] + R[(size_t)w * 40 + lane]) : -1e30f;
    float m = v;
    #pragma unroll
    for (int off = 32; off; off >>= 1) m = fmaxf(m, __shfl_xor(m, off, 64));
    float ex = act ? expf(v - m) : 0.f;
    float s = ex;
    #pragma unroll
    for (int off = 32; off; off >>= 1) s += __shfl_xor(s, off, 64);
    if (act) out[(size_t)w * 40 + lane] = ex / s;
}

extern "C" void kernel_launch(void* const* d_in, const int* in_sizes, int n_in,
                              void* d_out, int out_size, void* d_ws, size_t ws_size,
                              hipStream_t stream) {
    const float* x   = (const float*)d_in[0];
    const void*  ei  = d_in[1];
    const float* Wl0 = (const float*)d_in[2];
    const float* Wr0 = (const float*)d_in[3];
    const float* b0  = (const float*)d_in[4];
    const float* Wl1 = (const float*)d_in[5];
    const float* Wr1 = (const float*)d_in[6];
    const float* b1  = (const float*)d_in[7];
    const float* Wl2 = (const float*)d_in[8];
    const float* Wr2 = (const float*)d_in[9];
    const float* b2  = (const float*)d_in[10];
    float* out = (float*)d_out;

    char* ws = (char*)d_ws;
    int*   row_ptr = (int*)(ws + WS_ROWPTR);
    int*   deg     = (int*)(ws + WS_DEG);
    int*   fill    = (int*)(ws + WS_FILL);
    float* invd    = (float*)(ws + WS_INVDEG);
    int*   bsum    = (int*)(ws + WS_BSUM);
    int*   flag    = (int*)(ws + WS_FLAG);
    float* WlT0    = (float*)(ws + WS_WLT0);
    float* WrT0    = (float*)(ws + WS_WRT0);
    float* WlT1    = (float*)(ws + WS_WLT1);
    float* WrT1    = (float*)(ws + WS_WRT1);
    float* WcT2    = (float*)(ws + WS_WCT2);
    int*   col     = (int*)(ws + WS_COL);
    float* agg     = (float*)(ws + WS_AGG);
    float* h1      = (float*)(ws + WS_H1);
    float* h2      = (float*)(ws + WS_H2);
    float* P       = (float*)(ws + WS_P);
    float* R       = (float*)(ws + WS_R);

    // zero deg + fill (adjacent)
    hipMemsetAsync(ws + WS_DEG, 0, 800768, stream);

    k_detect<<<1, 256, 0, stream>>>(ei, flag);
    k_transpose<<<64, 256, 0, stream>>>(Wl0, Wr0, Wl1, Wr1, Wl2, Wr2,
                                        WlT0, WrT0, WlT1, WrT1, WcT2);
    k_hist<<<N_EDGES / 256, 256, 0, stream>>>(ei, flag, deg);
    k_scan1<<<98, 256, 0, stream>>>(deg, bsum);
    k_scan2<<<1, 64, 0, stream>>>(bsum, row_ptr, 98);
    k_scan3<<<98, 256, 0, stream>>>(deg, bsum, row_ptr);
    k_invdeg<<<391, 256, 0, stream>>>(row_ptr, invd);
    k_scatter<<<N_EDGES / 256, 256, 0, stream>>>(ei, flag, row_ptr, fill, col);

    // layer 0
    k_aggregate<<<25000, 256, 0, stream>>>(x, row_ptr, col, invd, agg);
    k_gemm_fused<<<1563, 256, 0, stream>>>(agg, x, WlT0, WrT0, b0, h1);
    // layer 1
    k_aggregate<<<25000, 256, 0, stream>>>(h1, row_ptr, col, invd, agg);
    k_gemm_fused<<<1563, 256, 0, stream>>>(agg, h1, WlT1, WrT1, b1, h2);
    // layer 2 (GEMM first, then aggregate the 40-dim projections)
    k_gemm2<<<782, 320, 0, stream>>>(h2, WcT2, b2, P, R);
    k_final<<<25000, 256, 0, stream>>>(P, R, row_ptr, col, invd, out);
}

// Round 8
// 779.462 us; speedup vs baseline: 1.1756x; 1.1756x over previous
//
#include <hip/hip_runtime.h>
#include <cstdint>
#include <cstddef>

#define N_NODES 100000
#define N_EDGES 1600000

// ---------------- workspace layout (byte offsets) ----------------
#define WS_ROWPTR   0            // (N+1) int
#define WS_DEG      400384       // N int
#define WS_FILL     800768       // N int
#define WS_INVDEG   1201152      // N float
#define WS_BSUM     1601536      // 98 int
#define WS_FLAG     1602560      // 1 int (1 = edge_index is int64)
#define WS_BP       1602816      // 4 x 64KB MFMA-frag-packed W (h 32KB + l 32KB each)
#define WS_WCT2     1864960      // 128x80 f ([k][o], o<40 -> Wl2, o>=40 -> Wr2)
#define WS_COL      1906176      // E int
#define WS_AGG      8306432      // N*128 u32 pack (51.2MB)
#define WS_H1       59506432     // N*128 u32 pack
#define WS_H2       110706432    // N*128 u32 pack
#define WS_XPACK    161906432    // N*128 u32 pack of x
#define WS_P        WS_AGG              // overlay (agg dead after layer-1 GEMM)
#define WS_R        (WS_AGG + 16000000) // N*40 f

typedef __attribute__((ext_vector_type(8))) short short8;
typedef __attribute__((ext_vector_type(4))) float floatx4;

// split fp32 into bf16 hi/lo, packed (hi in bits 31:16, lo bf16 bits in 15:0)
__device__ __forceinline__ unsigned pack_bf16x2(float x) {
    unsigned u = __float_as_uint(x);
    unsigned hi = (u + 0x7FFFu + ((u >> 16) & 1u)) & 0xFFFF0000u;
    float r = x - __uint_as_float(hi);
    unsigned ur = __float_as_uint(r);
    unsigned lo = (ur + 0x7FFFu + ((ur >> 16) & 1u)) >> 16;
    return hi | lo;
}
// reconstruct: hi + lo (error ~2^-17 relative)
__device__ __forceinline__ float unpk(unsigned u) {
    return __uint_as_float(u & 0xFFFF0000u) + __uint_as_float(u << 16);
}

__device__ __forceinline__ int edge_val(const void* ei, long long idx, int m64) {
    return m64 ? (int)((const long long*)ei)[idx] : ((const int*)ei)[idx];
}

// detect int32 vs int64 edge_index: int64 -> all odd 32-bit words are zero
__global__ void k_detect(const void* __restrict__ ei, int* __restrict__ flag) {
    __shared__ int s_any;
    if (threadIdx.x == 0) s_any = 0;
    __syncthreads();
    const int* p = (const int*)ei;
    int any = 0;
    for (int j = 0; j < 8; ++j) any |= p[2 * (threadIdx.x * 8 + j) + 1];
    if (any) s_any = 1;
    __syncthreads();
    if (threadIdx.x == 0) *flag = (s_any == 0) ? 1 : 0;
}

// WcT2 for layer-2 fp32 GEMM (unchanged path)
__global__ void k_transpose(const float* __restrict__ Wl2, const float* __restrict__ Wr2,
                            float* __restrict__ Tc) {
    int i = blockIdx.x * 256 + threadIdx.x;
    if (i < 10240) {
        int k = i / 80, o = i % 80;
        Tc[i] = (o < 40) ? Wl2[o * 128 + k] : Wr2[(o - 40) * 128 + k];
    }
}

// pack Wl0,Wr0,Wl1,Wr1 into MFMA B-fragment order, bf16 hi/lo planes.
// B[k][n] frag for 16x16x32: lane supplies n=lane&15, k=quad*8+j (j=0..7).
__global__ void k_packw(const float* __restrict__ Wl0, const float* __restrict__ Wr0,
                        const float* __restrict__ Wl1, const float* __restrict__ Wr1,
                        short* __restrict__ bp) {
    int t = blockIdx.x * 256 + threadIdx.x;     // 8192 tasks
    if (t >= 8192) return;
    int mat = t >> 11, rem = t & 2047;
    int kt = rem >> 9, nt = (rem >> 6) & 7, lane = rem & 63;
    const float* W = (mat == 0) ? Wl0 : (mat == 1) ? Wr0 : (mat == 2) ? Wl1 : Wr1;
    int n  = nt * 16 + (lane & 15);
    int kb = kt * 32 + (lane >> 4) * 8;
    short* dh = bp + mat * 32768 + ((size_t)(kt * 8 + nt) * 64 + lane) * 8;
    short* dl = dh + 16384;
    for (int j = 0; j < 8; ++j) {
        unsigned p = pack_bf16x2(W[n * 128 + kb + j]);  // W row-major [o][k]
        dh[j] = (short)(p >> 16);
        dl[j] = (short)(p & 0xFFFFu);
    }
}

// pack x (fp32) -> u32 hi/lo
__global__ void k_pack_x(const float4* __restrict__ x, uint4* __restrict__ xp) {
    int i = blockIdx.x * 256 + threadIdx.x;
    if (i < N_NODES * 32) {
        float4 v = x[i];
        xp[i] = make_uint4(pack_bf16x2(v.x), pack_bf16x2(v.y), pack_bf16x2(v.z), pack_bf16x2(v.w));
    }
}

__global__ void k_hist(const void* __restrict__ ei, const int* __restrict__ flag,
                       int* __restrict__ deg) {
    int m = *flag;
    int e = blockIdx.x * blockDim.x + threadIdx.x;
    if (e < N_EDGES) {
        int d = edge_val(ei, (long long)N_EDGES + e, m);
        atomicAdd(&deg[d], 1);
    }
}

__global__ void k_scan1(const int* __restrict__ deg, int* __restrict__ bsum) {
    __shared__ int sd[256];
    int t = threadIdx.x;
    int i0 = blockIdx.x * 1024 + t * 4;
    int s = 0;
    #pragma unroll
    for (int j = 0; j < 4; ++j) if (i0 + j < N_NODES) s += deg[i0 + j];
    sd[t] = s; __syncthreads();
    for (int off = 128; off; off >>= 1) {
        if (t < off) sd[t] += sd[t + off];
        __syncthreads();
    }
    if (t == 0) bsum[blockIdx.x] = sd[0];
}

__global__ void k_scan2(int* __restrict__ bsum, int* __restrict__ row_ptr, int nb) {
    if (threadIdx.x == 0 && blockIdx.x == 0) {
        int run = 0;
        for (int i = 0; i < nb; ++i) { int v = bsum[i]; bsum[i] = run; run += v; }
        row_ptr[N_NODES] = run;
    }
}

__global__ void k_scan3(const int* __restrict__ deg, const int* __restrict__ bsum,
                        int* __restrict__ row_ptr) {
    __shared__ int sd[256];
    int t = threadIdx.x;
    int i0 = blockIdx.x * 1024 + t * 4;
    int v[4]; int s = 0;
    #pragma unroll
    for (int j = 0; j < 4; ++j) { v[j] = (i0 + j < N_NODES) ? deg[i0 + j] : 0; s += v[j]; }
    sd[t] = s; __syncthreads();
    for (int off = 1; off < 256; off <<= 1) {
        int x = 0;
        if (t >= off) x = sd[t - off];
        __syncthreads();
        sd[t] += x;
        __syncthreads();
    }
    int run = bsum[blockIdx.x] + sd[t] - s;
    #pragma unroll
    for (int j = 0; j < 4; ++j) {
        if (i0 + j < N_NODES) row_ptr[i0 + j] = run;
        run += v[j];
    }
}

__global__ void k_invdeg(const int* __restrict__ row_ptr, float* __restrict__ invd) {
    int i = blockIdx.x * 256 + threadIdx.x;
    if (i < N_NODES) {
        int d = row_ptr[i + 1] - row_ptr[i];
        invd[i] = 1.0f / (float)(d > 1 ? d : 1);
    }
}

__global__ void k_scatter(const void* __restrict__ ei, const int* __restrict__ flag,
                          const int* __restrict__ row_ptr, int* __restrict__ fill,
                          int* __restrict__ col) {
    int m = *flag;
    int e = blockIdx.x * blockDim.x + threadIdx.x;
    if (e < N_EDGES) {
        int s = edge_val(ei, e, m);
        int d = edge_val(ei, (long long)N_EDGES + e, m);
        int pos = row_ptr[d] + atomicAdd(&fill[d], 1);
        col[pos] = s;
    }
}

// mean-aggregate packed rows: one wave per node, uint2 (2 packed cols) per lane
__global__ __launch_bounds__(256) void k_aggregate(
    const unsigned* __restrict__ h, const int* __restrict__ rowp,
    const int* __restrict__ col, const float* __restrict__ invd,
    unsigned* __restrict__ agg) {
    int w = blockIdx.x * 4 + (threadIdx.x >> 6);
    if (w >= N_NODES) return;
    int lane = threadIdx.x & 63;
    const uint2* hp = (const uint2*)h;
    int beg = rowp[w], end = rowp[w + 1];
    float x = 0.f, y = 0.f;
    int e = beg;
    for (; e + 8 <= end; e += 8) {
        int s0 = col[e], s1 = col[e + 1], s2 = col[e + 2], s3 = col[e + 3];
        int s4 = col[e + 4], s5 = col[e + 5], s6 = col[e + 6], s7 = col[e + 7];
        uint2 a = hp[(size_t)s0 * 64 + lane];
        uint2 b = hp[(size_t)s1 * 64 + lane];
        uint2 c = hp[(size_t)s2 * 64 + lane];
        uint2 d = hp[(size_t)s3 * 64 + lane];
        uint2 a2 = hp[(size_t)s4 * 64 + lane];
        uint2 b2 = hp[(size_t)s5 * 64 + lane];
        uint2 c2 = hp[(size_t)s6 * 64 + lane];
        uint2 d2 = hp[(size_t)s7 * 64 + lane];
        x += (unpk(a.x) + unpk(b.x)) + (unpk(c.x) + unpk(d.x))
           + (unpk(a2.x) + unpk(b2.x)) + (unpk(c2.x) + unpk(d2.x));
        y += (unpk(a.y) + unpk(b.y)) + (unpk(c.y) + unpk(d.y))
           + (unpk(a2.y) + unpk(b2.y)) + (unpk(c2.y) + unpk(d2.y));
    }
    for (; e < end; ++e) {
        uint2 a = hp[(size_t)col[e] * 64 + lane];
        x += unpk(a.x); y += unpk(a.y);
    }
    float id = invd[w];
    ((uint2*)agg)[(size_t)w * 64 + lane] =
        make_uint2(pack_bf16x2(x * id), pack_bf16x2(y * id));
}

// bf16x3 MFMA GEMM: out = relu(l2norm(agg@WlT + h@WrT + b)), packed u32 I/O.
// Wave owns 32 nodes (2 m-tiles of 16); 8 n-tiles cover 128 outs.
// A-frag (m=lane&15, k=quad*8+j) read from packed global rows; B-frags
// pre-packed (k_packw). 3 MFMAs per tile: Ah*Bh + Ah*Bl + Al*Bh.
// C/D: col(n)=lane&15, row(m)=quad*4+reg [m89-verified]. Epilogue l2norm via
// quad-shuffles, LDS transpose (per-wave private, zero __syncthreads).
__global__ __launch_bounds__(256) void k_gemm_mfma(
    const unsigned* __restrict__ Vpack, const unsigned* __restrict__ Hpack,
    const short* __restrict__ BL, const short* __restrict__ BR,
    const float* __restrict__ bias, unsigned* __restrict__ outp) {
    __shared__ unsigned sE[4 * 2048];   // 32 KB, 8KB per wave
    const int t = threadIdx.x, lane = t & 63, wv = t >> 6;
    const int mrow = lane & 15, kq = lane >> 4;
    int nb = blockIdx.x * 128 + wv * 32;
    if (nb > N_NODES - 32) nb = N_NODES - 32;   // tail: duplicate recompute, benign

    floatx4 acc[2][8];
    #pragma unroll
    for (int nt = 0; nt < 8; ++nt) {
        float bv = bias[nt * 16 + mrow];
        floatx4 b4 = {bv, bv, bv, bv};
        acc[0][nt] = b4; acc[1][nt] = b4;
    }

    #pragma unroll
    for (int ph = 0; ph < 2; ++ph) {
        const unsigned* Vp = ph ? Hpack : Vpack;
        const short* Bh  = ph ? BR : BL;
        const short* Blo = Bh + 16384;
        #pragma unroll
        for (int kt = 0; kt < 4; ++kt) {
            short8 Ah[2], Al[2];
            #pragma unroll
            for (int mt = 0; mt < 2; ++mt) {
                const unsigned* ap = Vp + (size_t)(nb + mt * 16 + mrow) * 128 + kt * 32 + kq * 8;
                uint4 a0 = *(const uint4*)ap;
                uint4 a1 = *(const uint4*)(ap + 4);
                unsigned ua[8] = {a0.x, a0.y, a0.z, a0.w, a1.x, a1.y, a1.z, a1.w};
                #pragma unroll
                for (int j = 0; j < 8; ++j) {
                    Ah[mt][j] = (short)(ua[j] >> 16);
                    Al[mt][j] = (short)(ua[j] & 0xFFFFu);
                }
            }
            #pragma unroll
            for (int nt = 0; nt < 8; ++nt) {
                short8 bh = *(const short8*)(Bh  + ((size_t)(kt * 8 + nt) * 64 + lane) * 8);
                short8 bl = *(const short8*)(Blo + ((size_t)(kt * 8 + nt) * 64 + lane) * 8);
                #pragma unroll
                for (int mt = 0; mt < 2; ++mt) {
                    acc[mt][nt] = __builtin_amdgcn_mfma_f32_16x16x32_bf16(Ah[mt], bh, acc[mt][nt], 0, 0, 0);
                    acc[mt][nt] = __builtin_amdgcn_mfma_f32_16x16x32_bf16(Ah[mt], bl, acc[mt][nt], 0, 0, 0);
                    acc[mt][nt] = __builtin_amdgcn_mfma_f32_16x16x32_bf16(Al[mt], bh, acc[mt][nt], 0, 0, 0);
                }
            }
        }
    }

    // epilogue: per m-tile, l2norm rows, relu, pack, LDS transpose, store
    unsigned* myE = sE + wv * 2048;
    #pragma unroll
    for (int mt = 0; mt < 2; ++mt) {
        float ss[4] = {0.f, 0.f, 0.f, 0.f};
        #pragma unroll
        for (int nt = 0; nt < 8; ++nt)
            #pragma unroll
            for (int r = 0; r < 4; ++r) ss[r] += acc[mt][nt][r] * acc[mt][nt][r];
        #pragma unroll
        for (int m = 1; m < 16; m <<= 1) {
            #pragma unroll
            for (int r = 0; r < 4; ++r) ss[r] += __shfl_xor(ss[r], m, 64);
        }
        float sc[4];
        #pragma unroll
        for (int r = 0; r < 4; ++r) sc[r] = 1.f / fmaxf(sqrtf(ss[r]), 1e-12f);
        #pragma unroll
        for (int nt = 0; nt < 8; ++nt)
            #pragma unroll
            for (int r = 0; r < 4; ++r) {
                float v = fmaxf(acc[mt][nt][r] * sc[r], 0.f);
                myE[(kq * 4 + r) * 128 + nt * 16 + mrow] = pack_bf16x2(v);
            }
        __builtin_amdgcn_wave_barrier();
        #pragma unroll
        for (int i = 0; i < 8; ++i) {
            int row = i * 2 + (lane >> 5);
            int colw = (lane & 31) * 4;
            uint4 d = *(const uint4*)(myE + row * 128 + colw);
            *(uint4*)(outp + (size_t)(nb + mt * 16 + row) * 128 + colw) = d;
        }
        __builtin_amdgcn_wave_barrier();
    }
}

// layer 2: P = h@Wl2T ; R = h@Wr2T + b2 (80 outs, cat-W in LDS), packed-u32 input
__global__ __launch_bounds__(320, 2) void k_gemm2(
    const unsigned* __restrict__ h, const float* __restrict__ WcatT,
    const float* __restrict__ b2, float* __restrict__ P, float* __restrict__ R) {
    __shared__ float sW[128 * 80];
    const int t = threadIdx.x;
    const int o4 = (t % 20) * 4;
    const int ng = t / 20;
    const int nb = blockIdx.x * 128 + ng * 8;
    #pragma unroll
    for (int j = 0; j < 8; ++j)
        ((float4*)sW)[t + 320 * j] = ((const float4*)WcatT)[t + 320 * j];
    __syncthreads();
    float4 binit = make_float4(0.f, 0.f, 0.f, 0.f);
    if (o4 >= 40) binit = *(const float4*)(b2 + (o4 - 40));
    float acc[8][4];
    #pragma unroll
    for (int j = 0; j < 8; ++j) { acc[j][0] = binit.x; acc[j][1] = binit.y; acc[j][2] = binit.z; acc[j][3] = binit.w; }
    const uint4* vrow[8];
    #pragma unroll
    for (int j = 0; j < 8; ++j) {
        int n = nb + j; n = n < N_NODES ? n : N_NODES - 1;
        vrow[j] = (const uint4*)(h + (size_t)n * 128);
    }
    #pragma unroll 4
    for (int kq = 0; kq < 32; ++kq) {
        const int k = kq * 4;
        float4 w0 = *(const float4*)(sW + (k + 0) * 80 + o4);
        float4 w1 = *(const float4*)(sW + (k + 1) * 80 + o4);
        float4 w2 = *(const float4*)(sW + (k + 2) * 80 + o4);
        float4 w3 = *(const float4*)(sW + (k + 3) * 80 + o4);
        #pragma unroll
        for (int j = 0; j < 8; ++j) {
            uint4 u = vrow[j][kq];
            float4 v = make_float4(unpk(u.x), unpk(u.y), unpk(u.z), unpk(u.w));
            acc[j][0] = fmaf(v.x, w0.x, fmaf(v.y, w1.x, fmaf(v.z, w2.x, fmaf(v.w, w3.x, acc[j][0]))));
            acc[j][1] = fmaf(v.x, w0.y, fmaf(v.y, w1.y, fmaf(v.z, w2.y, fmaf(v.w, w3.y, acc[j][1]))));
            acc[j][2] = fmaf(v.x, w0.z, fmaf(v.y, w1.z, fmaf(v.z, w2.z, fmaf(v.w, w3.z, acc[j][2]))));
            acc[j][3] = fmaf(v.x, w0.w, fmaf(v.y, w1.w, fmaf(v.z, w2.w, fmaf(v.w, w3.w, acc[j][3]))));
        }
    }
    #pragma unroll
    for (int j = 0; j < 8; ++j) {
        int n = nb + j;
        if (n < N_NODES) {
            float4 r = make_float4(acc[j][0], acc[j][1], acc[j][2], acc[j][3]);
            if (o4 < 40) *(float4*)(P + (size_t)n * 40 + o4) = r;
            else         *(float4*)(R + (size_t)n * 40 + (o4 - 40)) = r;
        }
    }
}

// final: logits = mean_agg(P[src]) + R; softmax over 40; one wave per node
__global__ __launch_bounds__(256) void k_final(
    const float* __restrict__ P, const float* __restrict__ R,
    const int* __restrict__ rowp, const int* __restrict__ col,
    const float* __restrict__ invd, float* __restrict__ out) {
    int w = blockIdx.x * 4 + (threadIdx.x >> 6);
    if (w >= N_NODES) return;
    int lane = threadIdx.x & 63;
    bool act = lane < 40;
    int beg = rowp[w], end = rowp[w + 1];
    float a0 = 0.f, a1 = 0.f, a2 = 0.f, a3 = 0.f;
    int e = beg;
    for (; e + 4 <= end; e += 4) {
        int s0 = col[e], s1 = col[e + 1], s2 = col[e + 2], s3 = col[e + 3];
        if (act) {
            a0 += P[(size_t)s0 * 40 + lane];
            a1 += P[(size_t)s1 * 40 + lane];
            a2 += P[(size_t)s2 * 40 + lane];
            a3 += P[(size_t)s3 * 40 + lane];
        }
    }
    for (; e < end; ++e) if (act) a0 += P[(size_t)col[e] * 40 + lane];
    float acc = (a0 + a1) + (a2 + a3);
    float v = act ? (acc * invd[w] + R[(size_t)w * 40 + lane]) : -1e30f;
    float m = v;
    #pragma unroll
    for (int off = 32; off; off >>= 1) m = fmaxf(m, __shfl_xor(m, off, 64));
    float ex = act ? expf(v - m) : 0.f;
    float s = ex;
    #pragma unroll
    for (int off = 32; off; off >>= 1) s += __shfl_xor(s, off, 64);
    if (act) out[(size_t)w * 40 + lane] = ex / s;
}

extern "C" void kernel_launch(void* const* d_in, const int* in_sizes, int n_in,
                              void* d_out, int out_size, void* d_ws, size_t ws_size,
                              hipStream_t stream) {
    const float* x   = (const float*)d_in[0];
    const void*  ei  = d_in[1];
    const float* Wl0 = (const float*)d_in[2];
    const float* Wr0 = (const float*)d_in[3];
    const float* b0  = (const float*)d_in[4];
    const float* Wl1 = (const float*)d_in[5];
    const float* Wr1 = (const float*)d_in[6];
    const float* b1  = (const float*)d_in[7];
    const float* Wl2 = (const float*)d_in[8];
    const float* Wr2 = (const float*)d_in[9];
    const float* b2  = (const float*)d_in[10];
    float* out = (float*)d_out;

    char* ws = (char*)d_ws;
    int*      row_ptr = (int*)(ws + WS_ROWPTR);
    int*      deg     = (int*)(ws + WS_DEG);
    int*      fill    = (int*)(ws + WS_FILL);
    float*    invd    = (float*)(ws + WS_INVDEG);
    int*      bsum    = (int*)(ws + WS_BSUM);
    int*      flag    = (int*)(ws + WS_FLAG);
    short*    bp      = (short*)(ws + WS_BP);
    float*    WcT2    = (float*)(ws + WS_WCT2);
    int*      col     = (int*)(ws + WS_COL);
    unsigned* aggp    = (unsigned*)(ws + WS_AGG);
    unsigned* h1p     = (unsigned*)(ws + WS_H1);
    unsigned* h2p     = (unsigned*)(ws + WS_H2);
    unsigned* xp      = (unsigned*)(ws + WS_XPACK);
    float*    P       = (float*)(ws + WS_P);
    float*    R       = (float*)(ws + WS_R);

    hipMemsetAsync(ws + WS_DEG, 0, 800768, stream);

    k_detect<<<1, 256, 0, stream>>>(ei, flag);
    k_transpose<<<40, 256, 0, stream>>>(Wl2, Wr2, WcT2);
    k_packw<<<32, 256, 0, stream>>>(Wl0, Wr0, Wl1, Wr1, bp);
    k_pack_x<<<12500, 256, 0, stream>>>((const float4*)x, (uint4*)xp);
    k_hist<<<N_EDGES / 256, 256, 0, stream>>>(ei, flag, deg);
    k_scan1<<<98, 256, 0, stream>>>(deg, bsum);
    k_scan2<<<1, 64, 0, stream>>>(bsum, row_ptr, 98);
    k_scan3<<<98, 256, 0, stream>>>(deg, bsum, row_ptr);
    k_invdeg<<<391, 256, 0, stream>>>(row_ptr, invd);
    k_scatter<<<N_EDGES / 256, 256, 0, stream>>>(ei, flag, row_ptr, fill, col);

    // layer 0
    k_aggregate<<<25000, 256, 0, stream>>>(xp, row_ptr, col, invd, aggp);
    k_gemm_mfma<<<782, 256, 0, stream>>>(aggp, xp, bp, bp + 32768, b0, h1p);
    // layer 1
    k_aggregate<<<25000, 256, 0, stream>>>(h1p, row_ptr, col, invd, aggp);
    k_gemm_mfma<<<782, 256, 0, stream>>>(aggp, h1p, bp + 2 * 32768, bp + 3 * 32768, b1, h2p);
    // layer 2 (GEMM first, then aggregate the 40-dim projections)
    k_gemm2<<<782, 320, 0, stream>>>(h2p, WcT2, b2, P, R);
    k_final<<<25000, 256, 0, stream>>>(P, R, row_ptr, col, invd, out);
}